// Round 1
// baseline (1033.333 us; speedup 1.0000x reference)
//
#include <hip/hip_runtime.h>

#define BB   32
#define EE   256
#define HH   64
#define WW   64
#define HIDN 256
#define KC   8

__device__ __forceinline__ float bflo(unsigned u) { return __uint_as_float(u << 16); }
__device__ __forceinline__ float bfhi(unsigned u) { return __uint_as_float(u & 0xffff0000u); }
__device__ __forceinline__ unsigned f2bf(float f) {
  unsigned u = __float_as_uint(f);
  u += 0x7fffu + ((u >> 16) & 1u);   // round-to-nearest-even
  return u >> 16;
}

// One workgroup = one (b,h) slice. 256 threads.
// Phases: query -> softmax -> xbar -> cv -> value GEMM -> gate -> out GEMM.
__global__ __launch_bounds__(256, 3) void sep_attn_fused(
    const float* __restrict__ x, const float* __restrict__ Wqkv,
    const float* __restrict__ bqkv, const float* __restrict__ Wout,
    const float* __restrict__ bout, float* __restrict__ out)
{
  __shared__ __align__(16) float    qpart[4 * 64];
  __shared__ __align__(16) float    ss[64];
  __shared__ __align__(16) float    xbar_s[EE];
  __shared__ __align__(16) float    cvs[EE];
  __shared__ __align__(16) float    wchunk[KC * 256];   // [kk][c]
  __shared__ __align__(16) float    xchunk[KC * 64];    // [kk][w]
  __shared__ __align__(16) unsigned gsu[EE * WW / 2];   // gated, bf16 x2 packed, [c][w]

  const int tid = threadIdx.x;
  const int bh  = blockIdx.x;
  const int b   = bh >> 6;
  const int h   = bh & 63;
  const int gbase = (b * EE) * 4096 + h * 64;   // x[b,c,h,w] = x[gbase + c*4096 + w]

  // ---- Phase 1: query partials (coalesced over w) ----
  {
    const int w  = tid & 63;
    const int cg = tid >> 6;            // wave-uniform -> Wqkv loads are scalar
    float q = 0.f;
    const float* xp = x + gbase + (cg * 64) * 4096 + w;
    #pragma unroll 8
    for (int cc = 0; cc < 64; ++cc)
      q = fmaf(Wqkv[cg * 64 + cc], xp[cc * 4096], q);
    qpart[cg * 64 + w] = q;
  }
  __syncthreads();

  // ---- Phase 2: softmax over the 64 w positions (one wave) ----
  if (tid < 64) {
    float q = qpart[tid] + qpart[64 + tid] + qpart[128 + tid] + qpart[192 + tid] + bqkv[0];
    float m = q;
    #pragma unroll
    for (int off = 32; off; off >>= 1) m = fmaxf(m, __shfl_xor(m, off));
    float e = expf(q - m);
    float s = e;
    #pragma unroll
    for (int off = 32; off; off >>= 1) s += __shfl_xor(s, off);
    ss[tid] = e / s;
  }
  __syncthreads();

  // ---- Phase 3: xbar[c] = sum_w score[w] * x[b,c,h,w]  (x re-read is L2-hot) ----
  {
    const int c = tid;
    float acc = 0.f;
    #pragma unroll
    for (int f = 0; f < 16; ++f) {
      float4 sv = *(const float4*)&ss[f * 4];                       // LDS broadcast
      float4 xv = *(const float4*)&x[gbase + c * 4096 + f * 4];
      acc += sv.x * xv.x + sv.y * xv.y + sv.z * xv.z + sv.w * xv.w;
    }
    xbar_s[c] = acc;
  }
  __syncthreads();

  // ---- Phase 4: cv[c] = Wk_row(c) . xbar + bk[c]  (key GEMM collapsed) ----
  {
    const int c = tid;
    const float* wk = Wqkv + (1 + c) * EE;
    float acc = 0.f;
    #pragma unroll 8
    for (int f = 0; f < 64; ++f) {
      float4 wv = *(const float4*)&wk[f * 4];
      float4 xb = *(const float4*)&xbar_s[f * 4];                   // LDS broadcast
      acc += wv.x * xb.x + wv.y * xb.y + wv.z * xb.z + wv.w * xb.w;
    }
    cvs[c] = acc + bqkv[1 + c];
  }
  // visibility of cvs guaranteed by syncs inside the GEMM loop below

  const int i = tid >> 3;   // channel group: c = i*8 .. i*8+7
  const int j = tid & 7;    // w group:       w = j*8 .. j*8+7

  // ---- Phase 5: value GEMM (256x64 tile, k over 256 input channels) ----
  float acc1[8][8];
  #pragma unroll
  for (int r = 0; r < 8; ++r)
    #pragma unroll
    for (int q = 0; q < 8; ++q) acc1[r][q] = 0.f;

  for (int k0 = 0; k0 < EE; k0 += KC) {
    __syncthreads();
    {
      const float* wrow = Wqkv + (257 + tid) * EE + k0;   // value weight rows
      float4 a0 = *(const float4*)&wrow[0];
      float4 a1 = *(const float4*)&wrow[4];
      wchunk[0*256 + tid] = a0.x; wchunk[1*256 + tid] = a0.y;
      wchunk[2*256 + tid] = a0.z; wchunk[3*256 + tid] = a0.w;
      wchunk[4*256 + tid] = a1.x; wchunk[5*256 + tid] = a1.y;
      wchunk[6*256 + tid] = a1.z; wchunk[7*256 + tid] = a1.w;
    }
    if (tid < 128) {
      const int c = tid >> 4, f4 = tid & 15;
      *(float4*)&xchunk[c * 64 + f4 * 4] =
          *(const float4*)&x[gbase + (k0 + c) * 4096 + f4 * 4];
    }
    __syncthreads();
    #pragma unroll
    for (int kk = 0; kk < KC; ++kk) {
      float av[8], xv[8];
      *(float4*)&av[0] = *(const float4*)&wchunk[kk*256 + i*8];
      *(float4*)&av[4] = *(const float4*)&wchunk[kk*256 + i*8 + 4];
      *(float4*)&xv[0] = *(const float4*)&xchunk[kk*64 + j*8];
      *(float4*)&xv[4] = *(const float4*)&xchunk[kk*64 + j*8 + 4];
      #pragma unroll
      for (int r = 0; r < 8; ++r)
        #pragma unroll
        for (int q = 0; q < 8; ++q)
          acc1[r][q] = fmaf(av[r], xv[q], acc1[r][q]);
    }
  }

  // ---- Phase 6: relu + gate, pack bf16 into LDS ----
  {
    float4 cva = *(const float4*)&cvs[i*8];
    float4 cvb = *(const float4*)&cvs[i*8 + 4];
    float cvv[8] = {cva.x, cva.y, cva.z, cva.w, cvb.x, cvb.y, cvb.z, cvb.w};
    #pragma unroll
    for (int r = 0; r < 8; ++r) {
      const int c = i*8 + r;
      const float bias = bqkv[257 + c];
      float g[8];
      #pragma unroll
      for (int q = 0; q < 8; ++q)
        g[q] = fmaxf(acc1[r][q] + bias, 0.f) * cvv[r];
      uint4 U;
      U.x = f2bf(g[0]) | (f2bf(g[1]) << 16);
      U.y = f2bf(g[2]) | (f2bf(g[3]) << 16);
      U.z = f2bf(g[4]) | (f2bf(g[5]) << 16);
      U.w = f2bf(g[6]) | (f2bf(g[7]) << 16);
      *(uint4*)&gsu[c * 32 + j * 4] = U;
    }
  }

  // ---- Phase 7: output GEMM (k over 256 gated channels) ----
  float acc2[8][8];
  #pragma unroll
  for (int r = 0; r < 8; ++r)
    #pragma unroll
    for (int q = 0; q < 8; ++q) acc2[r][q] = 0.f;

  for (int k0 = 0; k0 < HIDN; k0 += KC) {
    __syncthreads();   // also publishes gsu on first iter, protects wchunk reuse
    {
      const float* wrow = Wout + tid * HIDN + k0;
      float4 a0 = *(const float4*)&wrow[0];
      float4 a1 = *(const float4*)&wrow[4];
      wchunk[0*256 + tid] = a0.x; wchunk[1*256 + tid] = a0.y;
      wchunk[2*256 + tid] = a0.z; wchunk[3*256 + tid] = a0.w;
      wchunk[4*256 + tid] = a1.x; wchunk[5*256 + tid] = a1.y;
      wchunk[6*256 + tid] = a1.z; wchunk[7*256 + tid] = a1.w;
    }
    __syncthreads();
    #pragma unroll
    for (int kk = 0; kk < KC; ++kk) {
      float av[8], xv[8];
      *(float4*)&av[0] = *(const float4*)&wchunk[kk*256 + i*8];
      *(float4*)&av[4] = *(const float4*)&wchunk[kk*256 + i*8 + 4];
      uint4 gu = *(const uint4*)&gsu[(k0 + kk) * 32 + j * 4];
      xv[0] = bflo(gu.x); xv[1] = bfhi(gu.x);
      xv[2] = bflo(gu.y); xv[3] = bfhi(gu.y);
      xv[4] = bflo(gu.z); xv[5] = bfhi(gu.z);
      xv[6] = bflo(gu.w); xv[7] = bfhi(gu.w);
      #pragma unroll
      for (int r = 0; r < 8; ++r)
        #pragma unroll
        for (int q = 0; q < 8; ++q)
          acc2[r][q] = fmaf(av[r], xv[q], acc2[r][q]);
    }
  }

  // ---- Phase 8: bias + coalesced store ----
  {
    float4 bo0 = *(const float4*)&bout[i*8];
    float4 bo1 = *(const float4*)&bout[i*8 + 4];
    float bo[8] = {bo0.x, bo0.y, bo0.z, bo0.w, bo1.x, bo1.y, bo1.z, bo1.w};
    #pragma unroll
    for (int r = 0; r < 8; ++r) {
      const int o = i*8 + r;
      float* op = out + (b * EE + o) * 4096 + h * 64 + j * 8;
      float4 o0 = make_float4(acc2[r][0] + bo[r], acc2[r][1] + bo[r],
                              acc2[r][2] + bo[r], acc2[r][3] + bo[r]);
      float4 o1 = make_float4(acc2[r][4] + bo[r], acc2[r][5] + bo[r],
                              acc2[r][6] + bo[r], acc2[r][7] + bo[r]);
      *(float4*)&op[0] = o0;
      *(float4*)&op[4] = o1;
    }
  }
}

extern "C" void kernel_launch(void* const* d_in, const int* in_sizes, int n_in,
                              void* d_out, int out_size, void* d_ws, size_t ws_size,
                              hipStream_t stream) {
  const float* x    = (const float*)d_in[0];
  const float* Wqkv = (const float*)d_in[1];
  const float* bqkv = (const float*)d_in[2];
  const float* Wout = (const float*)d_in[3];
  const float* bout = (const float*)d_in[4];
  float* out = (float*)d_out;
  dim3 grid(BB * HH);   // 2048 workgroups, one per (b,h)
  dim3 block(256);
  hipLaunchKernelGGL(sep_attn_fused, grid, block, 0, stream,
                     x, Wqkv, bqkv, Wout, bout, out);
}